// Round 6
// baseline (2477.208 us; speedup 1.0000x reference)
//
#include <hip/hip_runtime.h>
#include <cstdint>

typedef _Float16 half_t;
typedef _Float16 half2_t __attribute__((ext_vector_type(2)));
typedef _Float16 h8_t __attribute__((ext_vector_type(8)));
typedef float f4_t __attribute__((ext_vector_type(4)));
typedef unsigned int uint32;
typedef uint32 uv16 __attribute__((ext_vector_type(16)));

static constexpr int B_ = 64, T_ = 1024;

#define DEV __device__ __forceinline__

DEV float fdot2f(half2_t a, half2_t b, float c) {
#if __has_builtin(__builtin_amdgcn_fdot2)
  return __builtin_amdgcn_fdot2(a, b, c, false);
#else
  return fmaf((float)a.x, (float)b.x, fmaf((float)a.y, (float)b.y, c));
#endif
}

DEV float fast_rcp(float x) { return __builtin_amdgcn_rcpf(x); }
DEV float sigmf(float x) { return fast_rcp(1.f + __expf(-x)); }
DEV float tanhf_(float x) { return 1.f - 2.f * fast_rcp(1.f + __expf(2.f * x)); }
DEV uint32 pack2(float a, float b) {
  half2_t h; h.x = (half_t)a; h.y = (half_t)b;
  return __builtin_bit_cast(uint32, h);
}
DEV half2_t bch2(uint32 u) { return __builtin_bit_cast(half2_t, u); }

DEV void gload_lds16(const void* g, void* l) {
  __builtin_amdgcn_global_load_lds(
      (const __attribute__((address_space(1))) uint32*)g,
      (__attribute__((address_space(3))) uint32*)l, 16, 0, 0);
}

// select element j (compile-time) from the (va,vb) 32-dword pair
#define WSEL(va, vb, j) bch2(((j) < 16) ? (va)[(j) & 15] : (vb)[((j) - 16) & 15])

// ---------------- weight packing (f32 -> packed f16) ----------------
__global__ __launch_bounds__(256) void pack_w(
    const float* __restrict__ w_ih_f, const float* __restrict__ w_ih_b,
    const float* __restrict__ mu_w, const float* __restrict__ lv_w,
    const float* __restrict__ sw_w1,
    const float* __restrict__ w_hh_f, const float* __restrict__ w_hh_b,
    const float* __restrict__ b_ih_f, const float* __restrict__ b_ih_b,
    const float* __restrict__ b_hh_f, const float* __restrict__ b_hh_b,
    const float* __restrict__ mu_b, const float* __restrict__ lv_b,
    const float* __restrict__ sw_b1,
    uint32* __restrict__ wihf, uint32* __restrict__ wihb,
    uint32* __restrict__ wchf, uint32* __restrict__ wchb, uint32* __restrict__ wce2,
    uint32* __restrict__ whh, uint32* __restrict__ w1z,
    float* __restrict__ biasc, float* __restrict__ biasf, float* __restrict__ biasb) {
  int id = blockIdx.x * 256 + threadIdx.x;
  if (id < 98304) { wihf[id] = pack2(w_ih_f[2*id], w_ih_f[2*id+1]); return; }
  id -= 98304;
  if (id < 98304) { wihb[id] = pack2(w_ih_b[2*id], w_ih_b[2*id+1]); return; }
  id -= 98304;
  if (id < 32768) {  // wchf (256x256): h_f columns of [mu_w|lv_w|w1_h]
    int n = id >> 7, c0 = (id & 127) * 2;
    const float* p = (n < 64)  ? mu_w + n * 512 + c0
                   : (n < 128) ? lv_w + (n - 64) * 512 + c0
                               : sw_w1 + (n - 128) * 832 + 256 + c0;
    wchf[id] = pack2(p[0], p[1]); return;
  }
  id -= 32768;
  if (id < 32768) {  // wchb (256x256): h_b columns
    int n = id >> 7, c0 = (id & 127) * 2;
    const float* p = (n < 64)  ? mu_w + n * 512 + 256 + c0
                   : (n < 128) ? lv_w + (n - 64) * 512 + 256 + c0
                               : sw_w1 + (n - 128) * 832 + 512 + c0;
    wchb[id] = pack2(p[0], p[1]); return;
  }
  id -= 32768;
  if (id < 16384) {  // wce2 (128x256): w1_e rows only
    int n = id >> 7, c0 = (id & 127) * 2;
    wce2[id] = pack2(sw_w1[n * 832 + c0], sw_w1[n * 832 + c0 + 1]); return;
  }
  id -= 16384;
  if (id < 196608) {  // whh3: [d][6 gates][16 e][1024 tid] layout
    int dd = id / 98304, q = id % 98304;
    int j = q >> 10, t2 = q & 1023;   // j = g*16+e
    int g = j >> 4, e = j & 15;
    int rr = t2 >> 3, pp = t2 & 7;
    int gi = g >> 1, i = g & 1;       // gi: 0=r,1=z,2=n ; i: unit within pair
    int row = 256 * gi + 2 * rr + i;
    int k0 = 2 * (pp * 16 + e);
    const float* w = dd ? w_hh_b : w_hh_f;
    whh[id] = pack2(w[row * 256 + k0], w[row * 256 + k0 + 1]);
    return;
  }
  id -= 196608;
  if (id < 4096) {  // w1z2: [64][64] thread-k layout, rows (k, k+64)
    int j = id >> 6, kk = id & 63;
    int row = (j < 32) ? kk : kk + 64;
    int jj = j & 31;
    w1z[id] = pack2(sw_w1[row * 832 + 768 + 2 * jj], sw_w1[row * 832 + 768 + 2 * jj + 1]);
    return;
  }
  id -= 4096;
  if (id < 256) {
    biasc[id] = (id < 64) ? mu_b[id] : (id < 128) ? lv_b[id - 64] : sw_b1[id - 128];
    return;
  }
  id -= 256;
  if (id < 768) { biasf[id] = b_ih_f[id] + (id < 512 ? b_hh_f[id] : 0.f); return; }
  id -= 768;
  if (id < 768) { biasb[id] = b_ih_b[id] + (id < 512 ? b_hh_b[id] : 0.f); return; }
}

// ---------------- GEMM: C(MxN) = A(MxK) * B(N,K)^T [+bias] [+=C] ----------------
template <int AF32, int ACC>
__global__ __launch_bounds__(256) void gemm_t(
    const void* __restrict__ Ap, int lda,
    const half_t* __restrict__ Bw,  // (N,K) f16 row-major
    const float* __restrict__ bias,
    half_t* __restrict__ C, int ldc, int K) {
  __shared__ __align__(16) half_t smem[16384];
  half_t* As = smem;         // [128][64]
  half_t* Bs = smem + 8192;  // [128][64]
  const int tid = threadIdx.x;
  const int lane = tid & 63, w = tid >> 6;
  const int n0 = blockIdx.x * 128, m0 = blockIdx.y * 128;
  const int r8 = lane >> 3, c8 = lane & 7;
  f4_t acc[4][4];
  f4_t zero = {0.f, 0.f, 0.f, 0.f};
#pragma unroll
  for (int i = 0; i < 4; ++i)
#pragma unroll
    for (int j = 0; j < 4; ++j) acc[i][j] = zero;
  const int wm = (w >> 1) * 64, wn = (w & 1) * 64;
  for (int ks = 0; ks < K; ks += 64) {
    if constexpr (AF32) {
      const float* Af = (const float*)Ap;
#pragma unroll
      for (int it = 0; it < 4; ++it) {
        int c = it * 256 + tid;
        int row = c >> 3, coff = (c & 7) * 8;
        const float* ap = Af + (size_t)(m0 + row) * lda + ks + coff;
        float4 v0 = *(const float4*)ap;
        float4 v1 = *(const float4*)(ap + 4);
        uint4 u;
        u.x = pack2(v0.x, v0.y); u.y = pack2(v0.z, v0.w);
        u.z = pack2(v1.x, v1.y); u.w = pack2(v1.z, v1.w);
        *(uint4*)&As[(size_t)c * 8] = u;
      }
    } else {
      const half_t* Af = (const half_t*)Ap;
#pragma unroll
      for (int c = 0; c < 4; ++c) {
        int row = w * 32 + c * 8 + r8;
        gload_lds16(Af + (size_t)(m0 + row) * lda + ks + c8 * 8, As + (w * 4 + c) * 512);
      }
    }
#pragma unroll
    for (int c = 0; c < 4; ++c) {
      int row = w * 32 + c * 8 + r8;
      gload_lds16(Bw + (size_t)(n0 + row) * K + ks + c8 * 8, Bs + (w * 4 + c) * 512);
    }
    __syncthreads();
#pragma unroll
    for (int kk = 0; kk < 2; ++kk) {
      h8_t af[4], bf[4];
      const int ko = kk * 32 + (lane >> 4) * 8;
#pragma unroll
      for (int i = 0; i < 4; ++i) af[i] = *(const h8_t*)&As[(wm + i * 16 + (lane & 15)) * 64 + ko];
#pragma unroll
      for (int j = 0; j < 4; ++j) bf[j] = *(const h8_t*)&Bs[(wn + j * 16 + (lane & 15)) * 64 + ko];
#pragma unroll
      for (int i = 0; i < 4; ++i)
#pragma unroll
        for (int j = 0; j < 4; ++j)
          acc[i][j] = __builtin_amdgcn_mfma_f32_16x16x32_f16(af[i], bf[j], acc[i][j], 0, 0, 0);
    }
    __syncthreads();
  }
  const int cl4 = lane & 15, rl4 = lane >> 4;
#pragma unroll
  for (int j = 0; j < 4; ++j) {
    float bj = bias ? bias[n0 + wn + j * 16 + cl4] : 0.f;
#pragma unroll
    for (int i = 0; i < 4; ++i)
#pragma unroll
      for (int q = 0; q < 4; ++q) {
        int rl = wm + i * 16 + rl4 * 4 + q;
        int cc = wn + j * 16 + cl4;
        smem[rl * 128 + cc] = (half_t)(acc[i][j][q] + bj);
      }
  }
  __syncthreads();
#pragma unroll
  for (int it = 0; it < 8; ++it) {
    int idx = it * 256 + tid;
    int row = idx >> 4, colc = idx & 15;
    uint4 v = *(const uint4*)&smem[row * 128 + colc * 8];
    half_t* cp = C + (size_t)(m0 + row) * ldc + n0 + colc * 8;
    if constexpr (ACC) {
      uint4 o = *(const uint4*)cp;
      h8_t vv = __builtin_bit_cast(h8_t, v) + __builtin_bit_cast(h8_t, o);
      v = __builtin_bit_cast(uint4, vv);
    }
    *(uint4*)cp = v;
  }
}

// ---------------- GRU recurrence: 1024 threads, 96 weight dwords/thread ----------------
// 128 WGs = (b, dir); 1024 threads = 128 r-groups (2 hidden units) x 8 K-slices.
// Demand ~118 VGPR fits the 128-reg budget (4 waves/EU) -> weights stay resident.
__global__ __launch_bounds__(1024, 4) void gru_rec(
    uint32* __restrict__ xp,          // [2][B][T][384] dwords (f16 pairs)
    const uint32* __restrict__ whh3,  // [2][6][16][1024]
    const float* __restrict__ bhh_f, const float* __restrict__ bhh_b) {
  const int wg = blockIdx.x;
  const int d = wg >> 6, b = wg & 63;
  const int tid = threadIdx.x;
  const int r = tid >> 3, p = tid & 7;
  // h broadcast: 8 slices x (16 data + 4 pad) dwords -> slice bases p*20,
  // banks {0,20,8,28,16,4,24,12}: conflict-free b128 reads.
  __shared__ uint32 hb[2][160];
  __shared__ uint32 xbuf[2][384];  // staged xp row (double-buffered)
  if (tid < 160) { hb[0][tid] = 0; }
  uv16 w0, w1, w2, w3, w4, w5;  // 96 dwords of weights, named vectors
  {
    const uint32* wp = whh3 + (size_t)d * 98304 + tid;
#define LDW(vec, g) _Pragma("unroll") for (int e = 0; e < 16; ++e) vec[e] = wp[((g) * 16 + e) * 1024];
    LDW(w0, 0) LDW(w1, 1) LDW(w2, 2) LDW(w3, 3) LDW(w4, 4) LDW(w5, 5)
#undef LDW
  }
  const float* bhh = d ? bhh_b : bhh_f;
  const float bhn0 = bhh[512 + 2 * r], bhn1 = bhh[512 + 2 * r + 1];
  uint32* xpu = xp + ((size_t)d * B_ + b) * T_ * 384;
  float h0 = 0.f, h1 = 0.f;
  const int dt = d ? -1 : 1;
  int t = d ? (T_ - 1) : 0;
  if (tid < 384) xbuf[0][tid] = xpu[(size_t)t * 384 + tid];
  __syncthreads();
  for (int step = 0; step < T_; ++step) {
    const int cur = step & 1;
    const int tn = (step < T_ - 1) ? (t + dt) : t;
    uint32 xv = 0;
    if (tid < 384) xv = xpu[(size_t)tn * 384 + tid];  // issue early (T14)
    float a0 = 0, a1 = 0, a2 = 0, a3 = 0, a4 = 0, a5 = 0;
    const uint32* hc = &hb[cur][p * 20];
#pragma unroll
    for (int c = 0; c < 4; ++c) {
      uint4 u = *(const uint4*)(hc + c * 4);
      half2_t g0 = bch2(u.x), g1 = bch2(u.y), g2 = bch2(u.z), g3 = bch2(u.w);
      const int e = c * 4;
      a0 = fdot2f(bch2(w0[e]), g0, a0); a0 = fdot2f(bch2(w0[e + 1]), g1, a0);
      a0 = fdot2f(bch2(w0[e + 2]), g2, a0); a0 = fdot2f(bch2(w0[e + 3]), g3, a0);
      a1 = fdot2f(bch2(w1[e]), g0, a1); a1 = fdot2f(bch2(w1[e + 1]), g1, a1);
      a1 = fdot2f(bch2(w1[e + 2]), g2, a1); a1 = fdot2f(bch2(w1[e + 3]), g3, a1);
      a2 = fdot2f(bch2(w2[e]), g0, a2); a2 = fdot2f(bch2(w2[e + 1]), g1, a2);
      a2 = fdot2f(bch2(w2[e + 2]), g2, a2); a2 = fdot2f(bch2(w2[e + 3]), g3, a2);
      a3 = fdot2f(bch2(w3[e]), g0, a3); a3 = fdot2f(bch2(w3[e + 1]), g1, a3);
      a3 = fdot2f(bch2(w3[e + 2]), g2, a3); a3 = fdot2f(bch2(w3[e + 3]), g3, a3);
      a4 = fdot2f(bch2(w4[e]), g0, a4); a4 = fdot2f(bch2(w4[e + 1]), g1, a4);
      a4 = fdot2f(bch2(w4[e + 2]), g2, a4); a4 = fdot2f(bch2(w4[e + 3]), g3, a4);
      a5 = fdot2f(bch2(w5[e]), g0, a5); a5 = fdot2f(bch2(w5[e + 1]), g1, a5);
      a5 = fdot2f(bch2(w5[e + 2]), g2, a5); a5 = fdot2f(bch2(w5[e + 3]), g3, a5);
    }
    a0 += __shfl_xor(a0, 1); a0 += __shfl_xor(a0, 2); a0 += __shfl_xor(a0, 4);
    a1 += __shfl_xor(a1, 1); a1 += __shfl_xor(a1, 2); a1 += __shfl_xor(a1, 4);
    a2 += __shfl_xor(a2, 1); a2 += __shfl_xor(a2, 2); a2 += __shfl_xor(a2, 4);
    a3 += __shfl_xor(a3, 1); a3 += __shfl_xor(a3, 2); a3 += __shfl_xor(a3, 4);
    a4 += __shfl_xor(a4, 1); a4 += __shfl_xor(a4, 2); a4 += __shfl_xor(a4, 4);
    a5 += __shfl_xor(a5, 1); a5 += __shfl_xor(a5, 2); a5 += __shfl_xor(a5, 4);
    if (p == 0) {
      half2_t xrv = bch2(xbuf[cur][r]);
      half2_t xzv = bch2(xbuf[cur][128 + r]);
      half2_t xnv = bch2(xbuf[cur][256 + r]);
      float r0 = sigmf((float)xrv.x + a0);
      float r1 = sigmf((float)xrv.y + a1);
      float z0 = sigmf((float)xzv.x + a2);
      float z1 = sigmf((float)xzv.y + a3);
      float n0 = tanhf_((float)xnv.x + r0 * (a4 + bhn0));
      float n1 = tanhf_((float)xnv.y + r1 * (a5 + bhn1));
      h0 = (1.f - z0) * n0 + z0 * h0;
      h1 = (1.f - z1) * n1 + z1 * h1;
      uint32 ph = pack2(h0, h1);
      hb[cur ^ 1][(r >> 4) * 20 + (r & 15)] = ph;
      xpu[(size_t)t * 384 + r] = ph;  // in-place h store (xr slot dead)
    }
    if (tid < 384) xbuf[cur ^ 1][tid] = xv;  // write late (T14)
    __syncthreads();
    t = tn;
  }
}

// ---------------- z_tilde + KL partials ----------------
__global__ __launch_bounds__(256) void zkl(const half_t* __restrict__ hp,  // stride 768
                                           const float* __restrict__ eps,
                                           float* __restrict__ ztil,
                                           float* __restrict__ klp) {
  const int blk = blockIdx.x, tid = threadIdx.x;
  const size_t bt = (size_t)blk * 4 + (tid >> 6);
  const int j = tid & 63;
  float mu = (float)hp[bt * 768 + j];
  float lv = (float)hp[bt * 768 + 64 + j];
  float ev = eps[bt * 64 + j];
  ztil[bt * 64 + j] = mu + __expf(0.5f * lv) * ev;
  float term = 1.f + lv - mu * mu - __expf(lv);
#pragma unroll
  for (int s = 1; s < 64; s <<= 1) term += __shfl_xor(term, s);
  __shared__ float red[4];
  if ((tid & 63) == 0) red[tid >> 6] = term;
  __syncthreads();
  if (tid == 0) klp[blk] = red[0] + red[1] + red[2] + red[3];
}

__global__ __launch_bounds__(256) void klred(const float* __restrict__ klp,
                                             float* __restrict__ out) {
  const int tid = threadIdx.x;
  float s = 0.f;
  for (int i = tid; i < 16384; i += 256) s += klp[i];
#pragma unroll
  for (int st = 1; st < 64; st <<= 1) s += __shfl_xor(s, st);
  __shared__ float red[4];
  if ((tid & 63) == 0) red[tid >> 6] = s;
  __syncthreads();
  if (tid == 0) out[0] = (red[0] + red[1] + red[2] + red[3]) * (-0.5f / 65536.f);
}

// ---------------- sequential z-scan: ONE wave per batch element ----------------
__global__ __launch_bounds__(64, 4) void z_scan(
    const half_t* __restrict__ hp,  // pre at col offset 128, stride 768
    const float* __restrict__ zt_arr,
    const uint32* __restrict__ w1z,  // [64][64] thread-k layout
    const float* __restrict__ sw_w2, const float* __restrict__ sw_b2,
    float* __restrict__ z_out, float* __restrict__ beta_out) {
  const int b = blockIdx.x;
  const int k = threadIdx.x;  // 0..63; owns hid rows k and k+64
  uv16 z0a, z0b, z1a, z1b;    // 64 weights in named vectors
  {
#define LDZ(vec, base)                                    \
  _Pragma("unroll") for (int e = 0; e < 16; ++e) vec[e] = \
      w1z[((base) + e) * 64 + k];
    LDZ(z0a, 0); LDZ(z0b, 16); LDZ(z1a, 32); LDZ(z1b, 48);
#undef LDZ
  }
  const float w2k0 = sw_w2[k], w2k1 = sw_w2[k + 64], b2 = sw_b2[0];
  __shared__ uint32 zbuf[2][32];
  if (k < 32) { zbuf[0][k] = 0; zbuf[1][k] = 0; }
  __syncthreads();
  float zf = 0.f;
  const size_t bt0 = (size_t)b * T_;
  float pre0n = (float)hp[bt0 * 768 + 128 + k];
  float pre1n = (float)hp[bt0 * 768 + 192 + k];
  float ztn = zt_arr[bt0 * 64 + k];
  for (int t = 0; t < T_; ++t) {
    const int cur = t & 1;
    const float pre0 = pre0n, pre1 = pre1n, zt = ztn;
    const int tn = (t < T_ - 1) ? t + 1 : t;
    pre0n = (float)hp[(bt0 + tn) * 768 + 128 + k];
    pre1n = (float)hp[(bt0 + tn) * 768 + 192 + k];
    ztn = zt_arr[(bt0 + tn) * 64 + k];
    float a0 = 0, a1 = 0, a2 = 0, a3 = 0;
#pragma unroll
    for (int q = 0; q < 8; ++q) {
      uint4 u = *(const uint4*)&zbuf[cur][q * 4];
      const int m = q * 4;
      a0 = fdot2f(WSEL(z0a, z0b, m),     bch2(u.x), a0);
      a1 = fdot2f(WSEL(z0a, z0b, m + 1), bch2(u.y), a1);
      a0 = fdot2f(WSEL(z0a, z0b, m + 2), bch2(u.z), a0);
      a1 = fdot2f(WSEL(z0a, z0b, m + 3), bch2(u.w), a1);
      a2 = fdot2f(WSEL(z1a, z1b, m),     bch2(u.x), a2);
      a3 = fdot2f(WSEL(z1a, z1b, m + 1), bch2(u.y), a3);
      a2 = fdot2f(WSEL(z1a, z1b, m + 2), bch2(u.z), a2);
      a3 = fdot2f(WSEL(z1a, z1b, m + 3), bch2(u.w), a3);
    }
    float hid0 = fmaxf(pre0 + a0 + a1, 0.f);
    float hid1 = fmaxf(pre1 + a2 + a3, 0.f);
    float v = fmaf(hid0, w2k0, hid1 * w2k1);
#pragma unroll
    for (int s = 1; s < 64; s <<= 1) v += __shfl_xor(v, s);
    const float beta = sigmf(v + b2);
    zf = beta * zt + (1.f - beta) * zf;
    z_out[(bt0 + t) * 64 + k] = zf;
    if (k == 0) beta_out[bt0 + t] = beta;
    float zo = __shfl_xor(zf, 1);
    if ((k & 1) == 0) zbuf[cur ^ 1][k >> 1] = pack2(zf, zo);
    asm volatile("s_waitcnt lgkmcnt(0)" ::: "memory");  // single-wave LDS ordering
  }
}

extern "C" void kernel_launch(void* const* d_in, const int* in_sizes, int n_in,
                              void* d_out, int out_size, void* d_ws, size_t ws_size,
                              hipStream_t stream) {
  (void)in_sizes; (void)n_in; (void)out_size;
  const float* e_seq  = (const float*)d_in[0];
  const float* eps    = (const float*)d_in[1];
  const float* w_ih_f = (const float*)d_in[2];
  const float* w_hh_f = (const float*)d_in[3];
  const float* b_ih_f = (const float*)d_in[4];
  const float* b_hh_f = (const float*)d_in[5];
  const float* w_ih_b = (const float*)d_in[6];
  const float* w_hh_b = (const float*)d_in[7];
  const float* b_ih_b = (const float*)d_in[8];
  const float* b_hh_b = (const float*)d_in[9];
  const float* mu_w   = (const float*)d_in[10];
  const float* mu_b   = (const float*)d_in[11];
  const float* lv_w   = (const float*)d_in[12];
  const float* lv_b   = (const float*)d_in[13];
  const float* sw_w1  = (const float*)d_in[14];
  const float* sw_b1  = (const float*)d_in[15];
  const float* sw_w2  = (const float*)d_in[16];
  const float* sw_b2  = (const float*)d_in[17];

  // workspace: [0,100663296) xpf; [100663296,201326592) xpb; tail: packed weights
  const size_t NEED = 201326592 + 1924096;
  if (ws_size < NEED) return;
  char* ws = (char*)d_ws;
  half_t* xpf = (half_t*)ws;
  half_t* xpb = (half_t*)(ws + 100663296);
  half_t* hp  = xpf + 512;                      // heads cols [512,768), stride 768
  float*  ztil = (float*)(ws + 100663296);      // alias xpb (dead after head passes)
  float*  klp  = (float*)(ws + 100663296 + 16777216);
  char* wr = ws + 201326592;
  uint32* wihf  = (uint32*)(wr);                //  393216 B
  uint32* wihb  = (uint32*)(wr + 393216);       //  393216 B
  uint32* wchf  = (uint32*)(wr + 786432);       //  131072 B
  uint32* wchb  = (uint32*)(wr + 917504);       //  131072 B
  uint32* wce2  = (uint32*)(wr + 1048576);      //   65536 B
  uint32* whh3  = (uint32*)(wr + 1114112);      //  786432 B
  uint32* w1z2  = (uint32*)(wr + 1900544);      //   16384 B
  float*  biasc = (float*)(wr + 1916928);       //    1024 B
  float*  biasf = (float*)(wr + 1917952);       //    3072 B
  float*  biasb = (float*)(wr + 1921024);       //    3072 B

  pack_w<<<1879, 256, 0, stream>>>(w_ih_f, w_ih_b, mu_w, lv_w, sw_w1, w_hh_f, w_hh_b,
                                   b_ih_f, b_ih_b, b_hh_f, b_hh_b, mu_b, lv_b, sw_b1,
                                   wihf, wihb, wchf, wchb, wce2, whh3, w1z2,
                                   biasc, biasf, biasb);
  gemm_t<1, 0><<<dim3(6, 512), 256, 0, stream>>>(e_seq, 256, (const half_t*)wihf, biasf, xpf, 768, 256);
  gemm_t<1, 0><<<dim3(6, 512), 256, 0, stream>>>(e_seq, 256, (const half_t*)wihb, biasb, xpb, 768, 256);
  gru_rec<<<128, 1024, 0, stream>>>((uint32*)ws, whh3, b_hh_f, b_hh_b);
  gemm_t<0, 0><<<dim3(2, 512), 256, 0, stream>>>(xpf, 768, (const half_t*)wchf, biasc, hp, 768, 256);
  gemm_t<0, 1><<<dim3(2, 512), 256, 0, stream>>>(xpb, 768, (const half_t*)wchb, nullptr, hp, 768, 256);
  gemm_t<1, 1><<<dim3(1, 512), 256, 0, stream>>>(e_seq, 256, (const half_t*)wce2, nullptr, hp + 128, 768, 256);
  zkl<<<16384, 256, 0, stream>>>(hp, eps, ztil, klp);
  klred<<<1, 256, 0, stream>>>(klp, (float*)d_out + 4194304);
  z_scan<<<64, 64, 0, stream>>>(hp, ztil, w1z2, sw_w2, sw_b2, (float*)d_out, (float*)d_out + 4194305);
}